// Round 20
// baseline (272.765 us; speedup 1.0000x reference)
//
#include <hip/hip_runtime.h>
#include <hip/hip_bf16.h>
#include <cstdint>

typedef __bf16 bf16;
typedef __bf16 bf16x8 __attribute__((ext_vector_type(8)));
typedef __bf16 bf16x4 __attribute__((ext_vector_type(4)));
typedef float f32x4 __attribute__((ext_vector_type(4)));

__device__ __forceinline__ void gld_lds16(const void* g, void* l) {
  __builtin_amdgcn_global_load_lds((const __attribute__((address_space(1))) void*)g,
                                   (__attribute__((address_space(3))) void*)l, 16, 0, 0);
}

enum { BIAS_NONE = 0, BIAS_COL = 1, BIAS_ROW = 2, BIAS_QK = 3 };
enum { OUT_BF16 = 0, OUT_F32_RESID = 1, OUT_EXP = 2, OUT_VTILED = 3 };

// C[M,N] = A[M,K] * B^T (B stored [N,K], K contiguous); 128x128 tile, 4 waves.
// BIAS_QK: writes q/k in fragment-tiled layout Qt/Kt[kc=c/8][row][c%8].
// OUT_VTILED: write C tiled as Vt[col/8][row][col%8] (direct-global B frags).
template<int BIAS_MODE, int OUT_MODE>
__global__ __launch_bounds__(256)
void gemm_bt(const bf16* __restrict__ A, long sA, int lda,
             const bf16* __restrict__ Bm, long sB, int ldb,
             void* __restrict__ Cv, long sC, int ldc,
             const float* __restrict__ bias, const float* __restrict__ bias2,
             const float* __restrict__ resid, long sR,
             int K, float scale)
{
  const int bm = blockIdx.x, bn = blockIdx.y, bz = blockIdx.z;
  const char* Ab = (const char*)(A + (long)bz * sA);
  const char* Bb = (const char*)(Bm + (long)bz * sB);
  const int tid = threadIdx.x;
  const int wave = tid >> 6, lane = tid & 63;
  const int wr = wave >> 1, wc = wave & 1;

  __shared__ __attribute__((aligned(128))) char lds[32768];
  char* ldsA = lds;
  char* ldsB = lds + 16384;

  uint32_t aoff[4], boff[4];
#pragma unroll
  for (int i = 0; i < 4; ++i) {
    uint32_t ra = (uint32_t)(wr * 64 + i * 16 + (lane & 15));
    uint32_t la = ra * 128u + (uint32_t)((lane >> 4) << 4);
    aoff[i] = la ^ ((la >> 3) & 0x70u);
    uint32_t rb = (uint32_t)(wc * 64 + i * 16 + (lane & 15));
    uint32_t lb = rb * 128u + (uint32_t)((lane >> 4) << 4);
    boff[i] = lb ^ ((lb >> 3) & 0x70u);
  }
  uint32_t srow[4], sinb[4];
#pragma unroll
  for (int t = 0; t < 4; ++t) {
    uint32_t paddr = (uint32_t)(((wave * 4 + t) * 64 + lane) * 16);
    uint32_t laddr = paddr ^ ((paddr >> 3) & 0x70u);
    srow[t] = laddr >> 7;
    sinb[t] = laddr & 127u;
  }

  const long ldab = (long)lda * 2, ldbb = (long)ldb * 2;
  const long arow0 = (long)bm * 128, brow0 = (long)bn * 128;
  f32x4 acc[4][4] = {};
  const int nK = K >> 6;
  for (int kt = 0; kt < nK; ++kt) {
    const long k0b = (long)kt * 128;
#pragma unroll
    for (int t = 0; t < 4; ++t) {
      gld_lds16(Ab + (arow0 + srow[t]) * ldab + k0b + sinb[t], ldsA + (wave * 4 + t) * 1024);
      gld_lds16(Bb + (brow0 + srow[t]) * ldbb + k0b + sinb[t], ldsB + (wave * 4 + t) * 1024);
    }
    __syncthreads();
#pragma unroll
    for (int kk = 0; kk < 2; ++kk) {
      bf16x8 af[4], bfr[4];
#pragma unroll
      for (int i = 0; i < 4; ++i) {
        af[i]  = *(const bf16x8*)(ldsA + (aoff[i] ^ (kk << 6)));
        bfr[i] = *(const bf16x8*)(ldsB + (boff[i] ^ (kk << 6)));
      }
#pragma unroll
      for (int mi = 0; mi < 4; ++mi)
#pragma unroll
        for (int ni = 0; ni < 4; ++ni)
          acc[mi][ni] = __builtin_amdgcn_mfma_f32_16x16x32_bf16(af[mi], bfr[ni], acc[mi][ni], 0, 0, 0);
    }
    __syncthreads();
  }

  const int cl = lane & 15, rq = lane >> 4;
  const long row0 = (long)bm * 128 + wr * 64;
  const long col0 = (long)bn * 128 + wc * 64;

  if constexpr (OUT_MODE == OUT_F32_RESID) {
    float* Co = (float*)Cv + (long)bz * sC;
    const float* X = resid + (long)bz * sR;
#pragma unroll
    for (int mi = 0; mi < 4; ++mi)
#pragma unroll
      for (int ni = 0; ni < 4; ++ni) {
        const long col = col0 + ni * 16 + cl;
#pragma unroll
        for (int j = 0; j < 4; ++j) {
          const long row = row0 + mi * 16 + rq * 4 + j;
          Co[row * ldc + col] = acc[mi][ni][j] + bias[row] + X[row * ldc + col];
        }
      }
  } else if constexpr (OUT_MODE == OUT_VTILED) {
    bf16* Vt = (bf16*)Cv + (long)bz * sC;
#pragma unroll
    for (int mi = 0; mi < 4; ++mi)
#pragma unroll
      for (int ni = 0; ni < 4; ++ni) {
        const long col = col0 + ni * 16 + cl;
#pragma unroll
        for (int j = 0; j < 4; ++j) {
          const long row = row0 + mi * 16 + rq * 4 + j;
          float v = acc[mi][ni][j] + bias[row];
          Vt[((col >> 3) * 512 + row) * 8 + (col & 7)] = (bf16)v;
        }
      }
  } else if constexpr (BIAS_MODE == BIAS_QK) {
    // tiled write: Qt/Kt[(c>>3)*4096 + row]*8 + (c&7), c = channel
    const bool isq = (col0 < 512);
    bf16* base = (bf16*)Cv + (long)bz * sC + (isq ? 0 : sR);
    const long csub = isq ? 0 : 512;
#pragma unroll
    for (int mi = 0; mi < 4; ++mi)
#pragma unroll
      for (int ni = 0; ni < 4; ++ni) {
        const long col = col0 + ni * 16 + cl;
        const long c = col - csub;
        const float bc = isq ? bias[col] * scale : bias2[c];
        const float vs = isq ? scale : 1.f;
#pragma unroll
        for (int j = 0; j < 4; ++j) {
          const long row = row0 + mi * 16 + rq * 4 + j;
          base[((c >> 3) * 4096 + row) * 8 + (c & 7)] = (bf16)(acc[mi][ni][j] * vs + bc);
        }
      }
  } else {
    bf16* Co = (bf16*)Cv + (long)bz * sC;
#pragma unroll
    for (int mi = 0; mi < 4; ++mi)
#pragma unroll
      for (int ni = 0; ni < 4; ++ni) {
        const long col = col0 + ni * 16 + cl;
        float bc = 0.f;
        if (BIAS_MODE == BIAS_COL) bc = bias[col] * scale;
#pragma unroll
        for (int j = 0; j < 4; ++j) {
          const long row = row0 + mi * 16 + rq * 4 + j;
          float v = acc[mi][ni][j] * (BIAS_MODE == BIAS_COL ? scale : 1.f) + bc;
          if (BIAS_MODE == BIAS_ROW) v += bias[row];
          if constexpr (OUT_MODE == OUT_EXP) v = __expf(v);
          Co[row * ldc + col] = (bf16)v;
        }
      }
  }
}

// P[128,128-tile] = exp(Q.K^T): NO LDS, NO barriers. Fragments direct from
// fragment-tiled Qt/Kt (coalesced 256B/16-lane group, L2-resident). Register
// double-buffer pinned by sched_barrier(0) between prefetch and MFMA cluster
// (r19 failure: without the fence the compiler sank the loads and collapsed
// the dbuf — VGPR 104 proved it; latency then hit every cluster).
__global__ __launch_bounds__(256, 2)
void gemm_s12(const bf16* __restrict__ Qt, long sQ,
              const bf16* __restrict__ Kt, long sK,
              bf16* __restrict__ S, long sS)
{
  constexpr int T = 8;
  const int bm = blockIdx.x, bn = blockIdx.y, bz = blockIdx.z;
  const char* Qb = (const char*)(Qt + (long)bz * sQ);
  const char* Kb = (const char*)(Kt + (long)bz * sK);
  const int tid = threadIdx.x, wave = tid >> 6, lane = tid & 63;
  const int wr = wave >> 1, wc = wave & 1;
  const int lg = lane >> 4, l15 = lane & 15;

  // frag byte offsets: addr = base + t*524288 + kk*262144 + off[]
  long aOff[4], bOff[4];
#pragma unroll
  for (int mi = 0; mi < 4; ++mi) {
    long row = (long)bm * 128 + wr * 64 + mi * 16 + l15;
    aOff[mi] = (long)lg * 65536 + row * 16;
  }
#pragma unroll
  for (int ni = 0; ni < 4; ++ni) {
    long row = (long)bn * 128 + wc * 64 + ni * 16 + l15;
    bOff[ni] = (long)lg * 65536 + row * 16;
  }

  f32x4 acc[4][4] = {};

  auto loadA = [&](bf16x8 (&a)[4][2], int t) {
#pragma unroll
    for (int mi = 0; mi < 4; ++mi)
#pragma unroll
      for (int kk = 0; kk < 2; ++kk)
        a[mi][kk] = *(const bf16x8*)(Qb + (long)t * 524288 + kk * 262144 + aOff[mi]);
  };
  auto loadB = [&](bf16x8 (&b)[4][2], int t) {
#pragma unroll
    for (int ni = 0; ni < 4; ++ni)
#pragma unroll
      for (int kk = 0; kk < 2; ++kk)
        b[ni][kk] = *(const bf16x8*)(Kb + (long)t * 524288 + kk * 262144 + bOff[ni]);
  };

  bf16x8 aE[4][2], bE[4][2], aO_[4][2], bO_[4][2];
  loadA(aE, 0); loadB(bE, 0);
  __builtin_amdgcn_sched_barrier(0);   // keep tile-0 loads issued ahead

  auto body = [&](int t, bf16x8 (&aC)[4][2], bf16x8 (&bC)[4][2],
                  bf16x8 (&aN)[4][2], bf16x8 (&bN)[4][2]) {
    if (t + 1 < T) { loadA(aN, t + 1); loadB(bN, t + 1); }
    // fence: loads may not sink below, MFMAs may not hoist above — pins the
    // register double-buffer (both buffers live; prefetch covers L2 latency)
    __builtin_amdgcn_sched_barrier(0);
    __builtin_amdgcn_s_setprio(1);
#pragma unroll
    for (int mi = 0; mi < 4; ++mi)
#pragma unroll
      for (int ni = 0; ni < 4; ++ni)
#pragma unroll
        for (int kk = 0; kk < 2; ++kk)
          acc[mi][ni] = __builtin_amdgcn_mfma_f32_16x16x32_bf16(aC[mi][kk], bC[ni][kk], acc[mi][ni], 0, 0, 0);
    __builtin_amdgcn_s_setprio(0);
    __builtin_amdgcn_sched_barrier(0);
  };

#pragma unroll 1
  for (int t2 = 0; t2 < T; t2 += 2) {
    body(t2, aE, bE, aO_, bO_);
    body(t2 + 1, aO_, bO_, aE, bE);
  }

  // epilogue: P = exp(acc), row-major
  const int cl = l15, rq = lg;
  const long row0 = (long)bm * 128 + wr * 64;
  const long col0 = (long)bn * 128 + wc * 64;
  bf16* Co = S + (long)bz * sS;
#pragma unroll
  for (int mi = 0; mi < 4; ++mi)
#pragma unroll
    for (int ni = 0; ni < 4; ++ni) {
      const long col = col0 + ni * 16 + cl;
#pragma unroll
      for (int j = 0; j < 4; ++j) {
        const long row = row0 + mi * 16 + rq * 4 + j;
        Co[row * 4096 + col] = (bf16)__expf(acc[mi][ni][j]);
      }
    }
}

// O[64 rows, 256 cols] = P-tile * Vt. (r18 proven, unchanged)
__global__ __launch_bounds__(256, 2)
void gemm_pv11(const bf16* __restrict__ P, long sA,
               const bf16* __restrict__ Vt, long sVt,
               bf16* __restrict__ O, long sC, int swz)
{
  constexpr int T = 64;
  extern __shared__ char lds[];
  char* ldsA = lds;            // 2 x 8192 : A(P) 64 rows x 128B (Lrow at end)

  int bm, bn, bz;
  if (swz) {
    const int bid = blockIdx.x;
    const int xcd = bid & 7;
    bz = xcd >> 1;
    bn = (bid >> 3) & 1;
    bm = ((bid >> 4) << 1) | (xcd & 1);
  } else { bm = blockIdx.x; bn = blockIdx.y; bz = blockIdx.z; }

  const char* Ab = (const char*)(P + (long)bz * sA) + (long)bm * 64 * 8192;
  const char* Btb = (const char*)(Vt + (long)bz * sVt);
  const int tid = threadIdx.x, wave = tid >> 6, lane = tid & 63;
  const int lg = lane >> 4, l15 = lane & 15;

  const uint32_t ar0 = (uint32_t)(tid >> 3), ac16 = (uint32_t)((tid & 7) * 16);
  const uint32_t aswz = (ar0 & 7) << 4;

  uint32_t aO[4];
#pragma unroll
  for (int mi = 0; mi < 4; ++mi) {
    uint32_t r = (uint32_t)(mi * 16 + l15);
    aO[mi] = r * 128 + (((uint32_t)(lg * 16)) ^ ((r & 7) << 4));
  }
  uint32_t colb[4];
#pragma unroll
  for (int ni = 0; ni < 4; ++ni) {
    uint32_t col = (uint32_t)(bn * 256 + wave * 64 + ni * 16 + l15);
    colb[ni] = col * 16 + (uint32_t)lg * 8192;
  }

  f32x4 acc[4][4] = {};
  float lsum0 = 0.f, lsum1 = 0.f;

  auto loadB = [&](bf16x8 (&b)[4][2], int t) {
#pragma unroll
    for (int ni = 0; ni < 4; ++ni)
#pragma unroll
      for (int kk = 0; kk < 2; ++kk)
        b[ni][kk] = *(const bf16x8*)(Btb + (long)t * 65536 + kk * 32768 + colb[ni]);
  };
  auto loadA0 = [&](int t) -> bf16x8 {
    return *(const bf16x8*)(Ab + (long)ar0 * 8192 + (long)t * 128 + ac16);
  };
  auto loadA1 = [&](int t) -> bf16x8 {
    return *(const bf16x8*)(Ab + (long)(32 + ar0) * 8192 + (long)t * 128 + ac16);
  };
  auto writeA = [&](uint32_t nb, bf16x8 p0, bf16x8 p1) {
#pragma unroll
    for (int j = 0; j < 8; ++j) {
      lsum0 += (float)p0[j];
      lsum1 += (float)p1[j];
    }
    *(bf16x8*)(ldsA + nb * 8192 + ar0 * 128 + (ac16 ^ aswz)) = p0;
    *(bf16x8*)(ldsA + nb * 8192 + (32 + ar0) * 128 + (ac16 ^ aswz)) = p1;
  };

  bf16x8 bE[4][2], bO_[4][2];
  bf16x8 an0, an1;

  loadB(bE, 0);
  an0 = loadA0(0); an1 = loadA1(0);
  writeA(0, an0, an1);
  an0 = loadA0(1); an1 = loadA1(1);
  asm volatile("s_waitcnt lgkmcnt(0)" ::: "memory");
  __builtin_amdgcn_sched_barrier(0);
  __builtin_amdgcn_s_barrier();

  auto body = [&](int t, bf16x8 (&bCur)[4][2], bf16x8 (&bNxt)[4][2]) {
    const uint32_t cur = (uint32_t)(t & 1), nxt = cur ^ 1u;

    if (t + 1 < T) loadB(bNxt, t + 1);
    bf16x8 af[4][2];
#pragma unroll
    for (int mi = 0; mi < 4; ++mi)
#pragma unroll
      for (int kk = 0; kk < 2; ++kk)
        af[mi][kk] = *(const bf16x8*)(ldsA + ((cur * 8192 + aO[mi]) ^ (uint32_t)(kk << 6)));
    if (t + 1 < T) writeA(nxt, an0, an1);
    if (t + 2 < T) { an0 = loadA0(t + 2); an1 = loadA1(t + 2); }

    __builtin_amdgcn_s_setprio(1);
#pragma unroll
    for (int mi = 0; mi < 4; ++mi)
#pragma unroll
      for (int ni = 0; ni < 4; ++ni)
#pragma unroll
        for (int kk = 0; kk < 2; ++kk)
          acc[mi][ni] = __builtin_amdgcn_mfma_f32_16x16x32_bf16(af[mi][kk], bCur[ni][kk], acc[mi][ni], 0, 0, 0);
    __builtin_amdgcn_s_setprio(0);

    if (t + 1 < T) {
      asm volatile("s_waitcnt lgkmcnt(0)" ::: "memory");
      __builtin_amdgcn_sched_barrier(0);
      __builtin_amdgcn_s_barrier();
    }
  };

#pragma unroll 1
  for (int t2 = 0; t2 < T; t2 += 2) {
    body(t2, bE, bO_);
    body(t2 + 1, bO_, bE);
  }

  lsum0 += __shfl_xor(lsum0, 1, 64);
  lsum0 += __shfl_xor(lsum0, 2, 64);
  lsum0 += __shfl_xor(lsum0, 4, 64);
  lsum1 += __shfl_xor(lsum1, 1, 64);
  lsum1 += __shfl_xor(lsum1, 2, 64);
  lsum1 += __shfl_xor(lsum1, 4, 64);
  float* Lrow = (float*)ldsA;
  if ((tid & 7) == 0) {
    Lrow[ar0] = lsum0;
    Lrow[32 + ar0] = lsum1;
  }
  __syncthreads();

  bf16* Co = O + (long)bz * sC + (long)bm * 64 * 512 + (long)bn * 256;
#pragma unroll
  for (int mi = 0; mi < 4; ++mi)
#pragma unroll
    for (int j = 0; j < 4; ++j) {
      const int row = mi * 16 + lg * 4 + j;
      const float invL = 1.f / Lrow[row];
#pragma unroll
      for (int ni = 0; ni < 4; ++ni) {
        const int col = wave * 64 + ni * 16 + l15;
        Co[(long)row * 512 + col] = (bf16)(acc[mi][ni][j] * invL);
      }
    }
}

// ---------------- groupnorm / converts ----------------
__global__ __launch_bounds__(256)
void gn_stats(const float* __restrict__ x, float* __restrict__ stats)
{
  const int bg = blockIdx.x;
  const float4* px = (const float4*)(x + (long)bg * 65536);
  float s1 = 0.f, s2 = 0.f;
  for (int i = threadIdx.x; i < 16384; i += 256) {
    float4 f = px[i];
    s1 += f.x + f.y + f.z + f.w;
    s2 += f.x * f.x + f.y * f.y + f.z * f.z + f.w * f.w;
  }
#pragma unroll
  for (int d = 32; d > 0; d >>= 1) {
    s1 += __shfl_xor(s1, d, 64);
    s2 += __shfl_xor(s2, d, 64);
  }
  __shared__ float r1[4], r2[4];
  const int wave = threadIdx.x >> 6, lane = threadIdx.x & 63;
  if (lane == 0) { r1[wave] = s1; r2[wave] = s2; }
  __syncthreads();
  if (threadIdx.x == 0) {
    float t1 = r1[0] + r1[1] + r1[2] + r1[3];
    float t2 = r2[0] + r2[1] + r2[2] + r2[3];
    float mean = t1 * (1.f / 65536.f);
    float var  = t2 * (1.f / 65536.f) - mean * mean;
    stats[bg * 2]     = mean;
    stats[bg * 2 + 1] = rsqrtf(var + 1e-6f);
  }
}

__global__ __launch_bounds__(256)
void gn_apply(const float* __restrict__ x, const float* __restrict__ stats,
              const float* __restrict__ gamma, const float* __restrict__ beta,
              bf16* __restrict__ hn)
{
  const int b = blockIdx.y;
  const int n0 = blockIdx.x * 64;
  __shared__ __attribute__((aligned(16))) char lt[65536];
  const int tid = threadIdx.x;
  for (int i = 0; i < 32; ++i) {
    int f = i * 256 + tid;
    int c = f >> 4;
    int n4 = f & 15;
    float4 xv = *(const float4*)(x + (((long)b * 512 + c) * 4096) + n0 + n4 * 4);
    int g = c >> 4;
    float mean = stats[(b * 32 + g) * 2];
    float rstd = stats[(b * 32 + g) * 2 + 1];
    float ga = gamma[c], be = beta[c];
    float y[4];
    y[0] = (xv.x - mean) * rstd * ga + be;
    y[1] = (xv.y - mean) * rstd * ga + be;
    y[2] = (xv.z - mean) * rstd * ga + be;
    y[3] = (xv.w - mean) * rstd * ga + be;
    uint32_t cb = (uint32_t)(c * 2);
#pragma unroll
    for (int jj = 0; jj < 4; ++jj) {
      uint32_t nl = (uint32_t)(n4 * 4 + jj);
      uint32_t phys = nl * 1024u + (cb ^ (((nl >> 2) & 7u) << 4));
      *(bf16*)(lt + phys) = (bf16)y[jj];
    }
  }
  __syncthreads();
  for (int i = 0; i < 16; ++i) {
    int j = i * 256 + tid;
    uint32_t row = (uint32_t)(j >> 6);
    uint32_t m = (uint32_t)(j & 63);
    uint32_t phys = row * 1024u + ((m * 16u) ^ (((row >> 2) & 7u) << 4));
    uint4 val = *(const uint4*)(lt + phys);
    *(uint4*)((char*)(hn + ((long)b * 4096 + n0 + row) * 512) + m * 16) = val;
  }
}

__global__ __launch_bounds__(256)
void conv_w4(const float* __restrict__ w0, const float* __restrict__ w1,
             const float* __restrict__ w2, const float* __restrict__ w3,
             bf16* __restrict__ dst)
{
  const int z = blockIdx.y;
  const float* src = (z == 0) ? w0 : (z == 1) ? w1 : (z == 2) ? w2 : w3;
  const int i = blockIdx.x * 256 + threadIdx.x;
  float4 f = ((const float4*)src)[i];
  bf16x4 o;
  o[0] = (bf16)f.x; o[1] = (bf16)f.y; o[2] = (bf16)f.z; o[3] = (bf16)f.w;
  ((bf16x4*)(dst))[(long)z * 65536 + i] = o;
}

extern "C" void kernel_launch(void* const* d_in, const int* in_sizes, int n_in,
                              void* d_out, int out_size, void* d_ws, size_t ws_size,
                              hipStream_t stream)
{
  const float* x     = (const float*)d_in[0];
  const float* gamma = (const float*)d_in[1];
  const float* beta  = (const float*)d_in[2];
  const float* wq = (const float*)d_in[3];
  const float* bq = (const float*)d_in[4];
  const float* wk = (const float*)d_in[5];
  const float* bk = (const float*)d_in[6];
  const float* wv = (const float*)d_in[7];
  const float* bv = (const float*)d_in[8];
  const float* wo = (const float*)d_in[9];
  const float* bo = (const float*)d_in[10];
  float* out = (float*)d_out;

  char* ws = (char*)d_ws;
  bf16* hn  = (bf16*)(ws + 0);          // [4][4096][512]
  bf16* q   = (bf16*)(ws + 16777216);   // [4] Qt[64 kc][4096][8] (scale folded)
  bf16* k   = (bf16*)(ws + 33554432);   // [4] Kt[64 kc][4096][8]
  bf16* v   = (bf16*)(ws + 50331648);   // [4] Vt[512 kc][512 col][8]
  bf16* O   = (bf16*)(ws + 67108864);   // [4][4096][512]
  bf16* wqb = (bf16*)(ws + 83886080);   // [1024][512] = wq||wk, then wv, wo
  bf16* wvb = (bf16*)(ws + 84934656);
  bf16* wob = (bf16*)(ws + 85458944);
  float* gstats = (float*)(ws + 85983232);  // 1 KB
  bf16* S   = (bf16*)(ws + 85984256);       // tier1 [4][4096][4096] bf16 (P after exp)

  const long sBC = 2097152;
  const long sS1 = 16777216;
  const long K_OFS = 8388608;  // q -> k element offset in ws
  const float scale = 0.044194173824159216f; // 512^-0.5

  const int LDS_PV = 16384;  // A dbuf only
  hipFuncSetAttribute(reinterpret_cast<const void*>(gemm_pv11),
                      hipFuncAttributeMaxDynamicSharedMemorySize, LDS_PV);

  conv_w4<<<dim3(256, 4), 256, 0, stream>>>(wq, wk, wv, wo, wqb);
  gn_stats<<<128, 256, 0, stream>>>(x, gstats);
  gn_apply<<<dim3(64, 4), 256, 0, stream>>>(x, gstats, gamma, beta, hn);

  // fused q|k projection -> fragment-tiled Qt/Kt (q gets scale folded)
  gemm_bt<BIAS_QK, OUT_BF16><<<dim3(32, 8, 4), 256, 0, stream>>>(
      hn, sBC, 512, wqb, 0, 512, q, sBC, 512,
      bq, bk, nullptr, K_OFS, 512, scale);
  // v-projection -> fragment-tiled Vt for pv11's direct-global B
  gemm_bt<BIAS_ROW, OUT_VTILED><<<dim3(4, 32, 4), 256, 0, stream>>>(
      wvb, 0, 512, hn, sBC, 512, v, sBC, 4096,
      bv, nullptr, nullptr, 0, 512, 1.f);

  const bool tier1 = ws_size >= (size_t)220202112;
  if (tier1) {
    // P = exp(Qt.Kt^T): no-LDS direct-global fragment GEMM (pinned pipeline)
    gemm_s12<<<dim3(32, 32, 4), 256, 0, stream>>>(q, sBC, k, sBC, S, sS1);
    gemm_pv11<<<dim3(512, 1, 1), 256, LDS_PV, stream>>>(
        S, sS1, v, sBC, O, sBC, 1);
  } else {
    for (int b = 0; b < 4; ++b) {
      gemm_s12<<<dim3(32, 32, 1), 256, 0, stream>>>(
          q + b * sBC, 0, k + b * sBC, 0, S, 0);
      gemm_pv11<<<dim3(64, 2, 1), 256, LDS_PV, stream>>>(
          S, 0, v + b * sBC, 0, O + b * sBC, 0, 0);
    }
  }

  // out[b,o,n] = wo[o,:] . O[b,n,:] + bo[o] + x[b,o,n]
  gemm_bt<BIAS_ROW, OUT_F32_RESID><<<dim3(4, 32, 4), 256, 0, stream>>>(
      wob, 0, 512, O, sBC, 512, out, sBC, 4096,
      bo, nullptr, x, sBC, 512, 1.f);
}

// Round 21
// 264.256 us; speedup vs baseline: 1.0322x; 1.0322x over previous
//
#include <hip/hip_runtime.h>
#include <hip/hip_bf16.h>
#include <cstdint>

typedef __bf16 bf16;
typedef __bf16 bf16x8 __attribute__((ext_vector_type(8)));
typedef __bf16 bf16x4 __attribute__((ext_vector_type(4)));
typedef float f32x4 __attribute__((ext_vector_type(4)));

__device__ __forceinline__ void gld_lds16(const void* g, void* l) {
  __builtin_amdgcn_global_load_lds((const __attribute__((address_space(1))) void*)g,
                                   (__attribute__((address_space(3))) void*)l, 16, 0, 0);
}

enum { BIAS_NONE = 0, BIAS_COL = 1, BIAS_ROW = 2, BIAS_QK = 3 };
enum { OUT_BF16 = 0, OUT_F32_RESID = 1, OUT_EXP = 2, OUT_VTILED = 3 };

// C[M,N] = A[M,K] * B^T (B stored [N,K], K contiguous); 128x128 tile, 4 waves.
// OUT_EXP: write exp(acc) bf16 (P directly; max-free softmax).
// OUT_VTILED: write C tiled as Vt[col/8][row][col%8] (direct-global B frags).
template<int BIAS_MODE, int OUT_MODE>
__global__ __launch_bounds__(256)
void gemm_bt(const bf16* __restrict__ A, long sA, int lda,
             const bf16* __restrict__ Bm, long sB, int ldb,
             void* __restrict__ Cv, long sC, int ldc,
             const float* __restrict__ bias, const float* __restrict__ bias2,
             const float* __restrict__ resid, long sR,
             int K, float scale)
{
  const int bm = blockIdx.x, bn = blockIdx.y, bz = blockIdx.z;
  const char* Ab = (const char*)(A + (long)bz * sA);
  const char* Bb = (const char*)(Bm + (long)bz * sB);
  const int tid = threadIdx.x;
  const int wave = tid >> 6, lane = tid & 63;
  const int wr = wave >> 1, wc = wave & 1;

  __shared__ __attribute__((aligned(128))) char lds[32768];
  char* ldsA = lds;
  char* ldsB = lds + 16384;

  uint32_t aoff[4], boff[4];
#pragma unroll
  for (int i = 0; i < 4; ++i) {
    uint32_t ra = (uint32_t)(wr * 64 + i * 16 + (lane & 15));
    uint32_t la = ra * 128u + (uint32_t)((lane >> 4) << 4);
    aoff[i] = la ^ ((la >> 3) & 0x70u);
    uint32_t rb = (uint32_t)(wc * 64 + i * 16 + (lane & 15));
    uint32_t lb = rb * 128u + (uint32_t)((lane >> 4) << 4);
    boff[i] = lb ^ ((lb >> 3) & 0x70u);
  }
  uint32_t srow[4], sinb[4];
#pragma unroll
  for (int t = 0; t < 4; ++t) {
    uint32_t paddr = (uint32_t)(((wave * 4 + t) * 64 + lane) * 16);
    uint32_t laddr = paddr ^ ((paddr >> 3) & 0x70u);
    srow[t] = laddr >> 7;
    sinb[t] = laddr & 127u;
  }

  const long ldab = (long)lda * 2, ldbb = (long)ldb * 2;
  const long arow0 = (long)bm * 128, brow0 = (long)bn * 128;
  f32x4 acc[4][4] = {};
  const int nK = K >> 6;
  for (int kt = 0; kt < nK; ++kt) {
    const long k0b = (long)kt * 128;
#pragma unroll
    for (int t = 0; t < 4; ++t) {
      gld_lds16(Ab + (arow0 + srow[t]) * ldab + k0b + sinb[t], ldsA + (wave * 4 + t) * 1024);
      gld_lds16(Bb + (brow0 + srow[t]) * ldbb + k0b + sinb[t], ldsB + (wave * 4 + t) * 1024);
    }
    __syncthreads();
#pragma unroll
    for (int kk = 0; kk < 2; ++kk) {
      bf16x8 af[4], bfr[4];
#pragma unroll
      for (int i = 0; i < 4; ++i) {
        af[i]  = *(const bf16x8*)(ldsA + (aoff[i] ^ (kk << 6)));
        bfr[i] = *(const bf16x8*)(ldsB + (boff[i] ^ (kk << 6)));
      }
#pragma unroll
      for (int mi = 0; mi < 4; ++mi)
#pragma unroll
        for (int ni = 0; ni < 4; ++ni)
          acc[mi][ni] = __builtin_amdgcn_mfma_f32_16x16x32_bf16(af[mi], bfr[ni], acc[mi][ni], 0, 0, 0);
    }
    __syncthreads();
  }

  const int cl = lane & 15, rq = lane >> 4;
  const long row0 = (long)bm * 128 + wr * 64;
  const long col0 = (long)bn * 128 + wc * 64;

  if constexpr (OUT_MODE == OUT_F32_RESID) {
    float* Co = (float*)Cv + (long)bz * sC;
    const float* X = resid + (long)bz * sR;
#pragma unroll
    for (int mi = 0; mi < 4; ++mi)
#pragma unroll
      for (int ni = 0; ni < 4; ++ni) {
        const long col = col0 + ni * 16 + cl;
#pragma unroll
        for (int j = 0; j < 4; ++j) {
          const long row = row0 + mi * 16 + rq * 4 + j;
          Co[row * ldc + col] = acc[mi][ni][j] + bias[row] + X[row * ldc + col];
        }
      }
  } else if constexpr (OUT_MODE == OUT_VTILED) {
    // C element (row, col) -> Vt[(col>>3)*512 + row]*8 + (col&7)
    bf16* Vt = (bf16*)Cv + (long)bz * sC;
#pragma unroll
    for (int mi = 0; mi < 4; ++mi)
#pragma unroll
      for (int ni = 0; ni < 4; ++ni) {
        const long col = col0 + ni * 16 + cl;
#pragma unroll
        for (int j = 0; j < 4; ++j) {
          const long row = row0 + mi * 16 + rq * 4 + j;
          float v = acc[mi][ni][j] + bias[row];
          Vt[((col >> 3) * 512 + row) * 8 + (col & 7)] = (bf16)v;
        }
      }
  } else if constexpr (BIAS_MODE == BIAS_QK) {
    const bool isq = (col0 < 512);
    bf16* base = (bf16*)Cv + (long)bz * sC + (isq ? 0 : sR);
    const long csub = isq ? 0 : 512;
#pragma unroll
    for (int mi = 0; mi < 4; ++mi)
#pragma unroll
      for (int ni = 0; ni < 4; ++ni) {
        const long col = col0 + ni * 16 + cl;
        const float bc = isq ? bias[col] * scale : bias2[col - 512];
        const float vs = isq ? scale : 1.f;
#pragma unroll
        for (int j = 0; j < 4; ++j) {
          const long row = row0 + mi * 16 + rq * 4 + j;
          base[row * ldc + (col - csub)] = (bf16)(acc[mi][ni][j] * vs + bc);
        }
      }
  } else {
    bf16* Co = (bf16*)Cv + (long)bz * sC;
#pragma unroll
    for (int mi = 0; mi < 4; ++mi)
#pragma unroll
      for (int ni = 0; ni < 4; ++ni) {
        const long col = col0 + ni * 16 + cl;
        float bc = 0.f;
        if (BIAS_MODE == BIAS_COL) bc = bias[col] * scale;
#pragma unroll
        for (int j = 0; j < 4; ++j) {
          const long row = row0 + mi * 16 + rq * 4 + j;
          float v = acc[mi][ni][j] * (BIAS_MODE == BIAS_COL ? scale : 1.f) + bc;
          if (BIAS_MODE == BIAS_ROW) v += bias[row];
          if constexpr (OUT_MODE == OUT_EXP) v = __expf(v);
          Co[row * ldc + col] = (bf16)v;
        }
      }
  }
}

// O[64 rows, 256 cols] = P-tile * Vt. P=exp(s) precomputed (OUT_EXP).
// B(V) read DIRECTLY from global in fragment-tiled layout Vt[kc][col][8]
// (coalesced 256B per 16-lane group, L2-resident 4MB/batch) — NO B LDS path.
// A(P) via LDS as pv7 (16KB dbuf, XOR swizzle, L fused into staging).
// B register double-buffer, 2-unrolled (static names, rule #20). Single
// barrier/iter protects only ldsA; no manual vmcnt (all loads reg-dest).
// 1-D grid 512: pair (bid, bid+8) same P-rows / other N-half / same XCD;
// 2 XCDs per batch (Vt L2-resident).
__global__ __launch_bounds__(256, 2)
void gemm_pv11(const bf16* __restrict__ P, long sA,
               const bf16* __restrict__ Vt, long sVt,
               bf16* __restrict__ O, long sC, int swz)
{
  constexpr int T = 64;
  extern __shared__ char lds[];
  char* ldsA = lds;            // 2 x 8192 : A(P) 64 rows x 128B (Lrow at end)

  int bm, bn, bz;
  if (swz) {
    const int bid = blockIdx.x;
    const int xcd = bid & 7;
    bz = xcd >> 1;
    bn = (bid >> 3) & 1;
    bm = ((bid >> 4) << 1) | (xcd & 1);
  } else { bm = blockIdx.x; bn = blockIdx.y; bz = blockIdx.z; }

  const char* Ab = (const char*)(P + (long)bz * sA) + (long)bm * 64 * 8192;
  const char* Btb = (const char*)(Vt + (long)bz * sVt);   // [512 kc][512 col][8] bf16
  const int tid = threadIdx.x, wave = tid >> 6, lane = tid & 63;
  const int lg = lane >> 4, l15 = lane & 15;

  // A staging: 2 slots/thread: rows r0=tid>>3, r1=32+r0; chunk c16=(tid&7)*16
  const uint32_t ar0 = (uint32_t)(tid >> 3), ac16 = (uint32_t)((tid & 7) * 16);
  const uint32_t aswz = (ar0 & 7) << 4;

  // A fragment LDS offsets
  uint32_t aO[4];
#pragma unroll
  for (int mi = 0; mi < 4; ++mi) {
    uint32_t r = (uint32_t)(mi * 16 + l15);
    aO[mi] = r * 128 + (((uint32_t)(lg * 16)) ^ ((r & 7) << 4));
  }
  // B fragment global byte offsets: addr = t*65536 + kk*32768 + colb[ni]
  uint32_t colb[4];
#pragma unroll
  for (int ni = 0; ni < 4; ++ni) {
    uint32_t col = (uint32_t)(bn * 256 + wave * 64 + ni * 16 + l15);
    colb[ni] = col * 16 + (uint32_t)lg * 8192;
  }

  f32x4 acc[4][4] = {};
  float lsum0 = 0.f, lsum1 = 0.f;

  auto loadB = [&](bf16x8 (&b)[4][2], int t) {
#pragma unroll
    for (int ni = 0; ni < 4; ++ni)
#pragma unroll
      for (int kk = 0; kk < 2; ++kk)
        b[ni][kk] = *(const bf16x8*)(Btb + (long)t * 65536 + kk * 32768 + colb[ni]);
  };
  auto loadA0 = [&](int t) -> bf16x8 {
    return *(const bf16x8*)(Ab + (long)ar0 * 8192 + (long)t * 128 + ac16);
  };
  auto loadA1 = [&](int t) -> bf16x8 {
    return *(const bf16x8*)(Ab + (long)(32 + ar0) * 8192 + (long)t * 128 + ac16);
  };
  auto writeA = [&](uint32_t nb, bf16x8 p0, bf16x8 p1) {
#pragma unroll
    for (int j = 0; j < 8; ++j) {
      lsum0 += (float)p0[j];
      lsum1 += (float)p1[j];
    }
    *(bf16x8*)(ldsA + nb * 8192 + ar0 * 128 + (ac16 ^ aswz)) = p0;
    *(bf16x8*)(ldsA + nb * 8192 + (32 + ar0) * 128 + (ac16 ^ aswz)) = p1;
  };

  bf16x8 bE[4][2], bO_[4][2];
  bf16x8 an0, an1;

  // prologue: B(0) + A(0) in flight; A(0) staged; A(1) in flight
  loadB(bE, 0);
  an0 = loadA0(0); an1 = loadA1(0);
  writeA(0, an0, an1);                       // waits A(0) arrival (compiler)
  an0 = loadA0(1); an1 = loadA1(1);
  asm volatile("s_waitcnt lgkmcnt(0)" ::: "memory");
  __builtin_amdgcn_sched_barrier(0);
  __builtin_amdgcn_s_barrier();

  auto body = [&](int t, bf16x8 (&bCur)[4][2], bf16x8 (&bNxt)[4][2]) {
    const uint32_t cur = (uint32_t)(t & 1), nxt = cur ^ 1u;

    // 1. issue next B-frag loads (regs; consumed next iter)
    if (t + 1 < T) loadB(bNxt, t + 1);
    // 2. A fragment reads from buf[cur]
    bf16x8 af[4][2];
#pragma unroll
    for (int mi = 0; mi < 4; ++mi)
#pragma unroll
      for (int kk = 0; kk < 2; ++kk)
        af[mi][kk] = *(const bf16x8*)(ldsA + ((cur * 8192 + aO[mi]) ^ (uint32_t)(kk << 6)));
    // 3. write P(t+1) into ldsA[nxt] (compiler waits A(t+1) regs)
    if (t + 1 < T) writeA(nxt, an0, an1);
    // 4. issue A(t+2) register loads
    if (t + 2 < T) { an0 = loadA0(t + 2); an1 = loadA1(t + 2); }

    // 5. MFMA cluster (bCur arrived during previous iteration)
    __builtin_amdgcn_s_setprio(1);
#pragma unroll
    for (int mi = 0; mi < 4; ++mi)
#pragma unroll
      for (int ni = 0; ni < 4; ++ni)
#pragma unroll
        for (int kk = 0; kk < 2; ++kk)
          acc[mi][ni] = __builtin_amdgcn_mfma_f32_16x16x32_bf16(af[mi][kk], bCur[ni][kk], acc[mi][ni], 0, 0, 0);
    __builtin_amdgcn_s_setprio(0);

    // 6. single sync point: writeA visible; A(cur) reads done (consumed above)
    if (t + 1 < T) {
      asm volatile("s_waitcnt lgkmcnt(0)" ::: "memory");
      __builtin_amdgcn_sched_barrier(0);
      __builtin_amdgcn_s_barrier();
    }
  };

#pragma unroll 1
  for (int t2 = 0; t2 < T; t2 += 2) {
    body(t2, bE, bO_);
    body(t2 + 1, bO_, bE);
  }

  // L: reduce over the 8 threads sharing each row, stage in retired ldsA
  lsum0 += __shfl_xor(lsum0, 1, 64);
  lsum0 += __shfl_xor(lsum0, 2, 64);
  lsum0 += __shfl_xor(lsum0, 4, 64);
  lsum1 += __shfl_xor(lsum1, 1, 64);
  lsum1 += __shfl_xor(lsum1, 2, 64);
  lsum1 += __shfl_xor(lsum1, 4, 64);
  float* Lrow = (float*)ldsA;
  if ((tid & 7) == 0) {
    Lrow[ar0] = lsum0;
    Lrow[32 + ar0] = lsum1;
  }
  __syncthreads();

  // epilogue: scale by 1/L, write O half
  bf16* Co = O + (long)bz * sC + (long)bm * 64 * 512 + (long)bn * 256;
#pragma unroll
  for (int mi = 0; mi < 4; ++mi)
#pragma unroll
    for (int j = 0; j < 4; ++j) {
      const int row = mi * 16 + lg * 4 + j;
      const float invL = 1.f / Lrow[row];
#pragma unroll
      for (int ni = 0; ni < 4; ++ni) {
        const int col = wave * 64 + ni * 16 + l15;
        Co[(long)row * 512 + col] = (bf16)(acc[mi][ni][j] * invL);
      }
    }
}

// ---------------- groupnorm / converts ----------------
__global__ __launch_bounds__(256)
void gn_stats(const float* __restrict__ x, float* __restrict__ stats)
{
  const int bg = blockIdx.x;
  const float4* px = (const float4*)(x + (long)bg * 65536);
  float s1 = 0.f, s2 = 0.f;
  for (int i = threadIdx.x; i < 16384; i += 256) {
    float4 f = px[i];
    s1 += f.x + f.y + f.z + f.w;
    s2 += f.x * f.x + f.y * f.y + f.z * f.z + f.w * f.w;
  }
#pragma unroll
  for (int d = 32; d > 0; d >>= 1) {
    s1 += __shfl_xor(s1, d, 64);
    s2 += __shfl_xor(s2, d, 64);
  }
  __shared__ float r1[4], r2[4];
  const int wave = threadIdx.x >> 6, lane = threadIdx.x & 63;
  if (lane == 0) { r1[wave] = s1; r2[wave] = s2; }
  __syncthreads();
  if (threadIdx.x == 0) {
    float t1 = r1[0] + r1[1] + r1[2] + r1[3];
    float t2 = r2[0] + r2[1] + r2[2] + r2[3];
    float mean = t1 * (1.f / 65536.f);
    float var  = t2 * (1.f / 65536.f) - mean * mean;
    stats[bg * 2]     = mean;
    stats[bg * 2 + 1] = rsqrtf(var + 1e-6f);
  }
}

__global__ __launch_bounds__(256)
void gn_apply(const float* __restrict__ x, const float* __restrict__ stats,
              const float* __restrict__ gamma, const float* __restrict__ beta,
              bf16* __restrict__ hn)
{
  const int b = blockIdx.y;
  const int n0 = blockIdx.x * 64;
  __shared__ __attribute__((aligned(16))) char lt[65536];
  const int tid = threadIdx.x;
  for (int i = 0; i < 32; ++i) {
    int f = i * 256 + tid;
    int c = f >> 4;
    int n4 = f & 15;
    float4 xv = *(const float4*)(x + (((long)b * 512 + c) * 4096) + n0 + n4 * 4);
    int g = c >> 4;
    float mean = stats[(b * 32 + g) * 2];
    float rstd = stats[(b * 32 + g) * 2 + 1];
    float ga = gamma[c], be = beta[c];
    float y[4];
    y[0] = (xv.x - mean) * rstd * ga + be;
    y[1] = (xv.y - mean) * rstd * ga + be;
    y[2] = (xv.z - mean) * rstd * ga + be;
    y[3] = (xv.w - mean) * rstd * ga + be;
    uint32_t cb = (uint32_t)(c * 2);
#pragma unroll
    for (int jj = 0; jj < 4; ++jj) {
      uint32_t nl = (uint32_t)(n4 * 4 + jj);
      uint32_t phys = nl * 1024u + (cb ^ (((nl >> 2) & 7u) << 4));
      *(bf16*)(lt + phys) = (bf16)y[jj];
    }
  }
  __syncthreads();
  for (int i = 0; i < 16; ++i) {
    int j = i * 256 + tid;
    uint32_t row = (uint32_t)(j >> 6);
    uint32_t m = (uint32_t)(j & 63);
    uint32_t phys = row * 1024u + ((m * 16u) ^ (((row >> 2) & 7u) << 4));
    uint4 val = *(const uint4*)(lt + phys);
    *(uint4*)((char*)(hn + ((long)b * 4096 + n0 + row) * 512) + m * 16) = val;
  }
}

__global__ __launch_bounds__(256)
void conv_w4(const float* __restrict__ w0, const float* __restrict__ w1,
             const float* __restrict__ w2, const float* __restrict__ w3,
             bf16* __restrict__ dst)
{
  const int z = blockIdx.y;
  const float* src = (z == 0) ? w0 : (z == 1) ? w1 : (z == 2) ? w2 : w3;
  const int i = blockIdx.x * 256 + threadIdx.x;
  float4 f = ((const float4*)src)[i];
  bf16x4 o;
  o[0] = (bf16)f.x; o[1] = (bf16)f.y; o[2] = (bf16)f.z; o[3] = (bf16)f.w;
  ((bf16x4*)(dst))[(long)z * 65536 + i] = o;
}

extern "C" void kernel_launch(void* const* d_in, const int* in_sizes, int n_in,
                              void* d_out, int out_size, void* d_ws, size_t ws_size,
                              hipStream_t stream)
{
  const float* x     = (const float*)d_in[0];
  const float* gamma = (const float*)d_in[1];
  const float* beta  = (const float*)d_in[2];
  const float* wq = (const float*)d_in[3];
  const float* bq = (const float*)d_in[4];
  const float* wk = (const float*)d_in[5];
  const float* bk = (const float*)d_in[6];
  const float* wv = (const float*)d_in[7];
  const float* bv = (const float*)d_in[8];
  const float* wo = (const float*)d_in[9];
  const float* bo = (const float*)d_in[10];
  float* out = (float*)d_out;

  char* ws = (char*)d_ws;
  bf16* hn  = (bf16*)(ws + 0);          // [4][4096][512]
  bf16* q   = (bf16*)(ws + 16777216);   // [4][4096][512] (pre-scaled by 1/sqrt(512))
  bf16* k   = (bf16*)(ws + 33554432);   // [4][4096][512]
  bf16* v   = (bf16*)(ws + 50331648);   // [4] Vt[512 kc][512 col][8] bf16 (tiled)
  bf16* O   = (bf16*)(ws + 67108864);   // [4][4096][512]
  bf16* wqb = (bf16*)(ws + 83886080);   // [1024][512] = wq||wk, then wv, wo
  bf16* wvb = (bf16*)(ws + 84934656);
  bf16* wob = (bf16*)(ws + 85458944);
  float* gstats = (float*)(ws + 85983232);  // 1 KB
  bf16* S   = (bf16*)(ws + 85984256);       // tier1 [4][4096][4096] bf16 (P after exp)

  const long sBC = 2097152;
  const long sS1 = 16777216;
  const long K_OFS = 8388608;  // q -> k element offset in ws
  const float scale = 0.044194173824159216f; // 512^-0.5

  const int LDS_PV = 16384;  // A dbuf only
  hipFuncSetAttribute(reinterpret_cast<const void*>(gemm_pv11),
                      hipFuncAttributeMaxDynamicSharedMemorySize, LDS_PV);

  conv_w4<<<dim3(256, 4), 256, 0, stream>>>(wq, wk, wv, wo, wqb);
  gn_stats<<<128, 256, 0, stream>>>(x, gstats);
  gn_apply<<<dim3(64, 4), 256, 0, stream>>>(x, gstats, gamma, beta, hn);

  // fused q|k projection: B = stacked [1024][512] weights; q gets scale folded
  gemm_bt<BIAS_QK, OUT_BF16><<<dim3(32, 8, 4), 256, 0, stream>>>(
      hn, sBC, 512, wqb, 0, 512, q, sBC, 512,
      bq, bk, nullptr, K_OFS, 512, scale);
  // v-projection -> fragment-tiled Vt layout for pv11's direct-global B
  gemm_bt<BIAS_ROW, OUT_VTILED><<<dim3(4, 32, 4), 256, 0, stream>>>(
      wvb, 0, 512, hn, sBC, 512, v, sBC, 4096,
      bv, nullptr, nullptr, 0, 512, 1.f);

  const bool tier1 = ws_size >= (size_t)220202112;
  if (tier1) {
    // P = exp(q.k^T) directly (max-free softmax; s bounded ~±10 for this op)
    gemm_bt<BIAS_NONE, OUT_EXP><<<dim3(32, 32, 4), 256, 0, stream>>>(
        q, sBC, 512, k, sBC, 512, S, sS1, 4096,
        nullptr, nullptr, nullptr, 0, 512, 1.f);
    gemm_pv11<<<dim3(512, 1, 1), 256, LDS_PV, stream>>>(
        S, sS1, v, sBC, O, sBC, 1);
  } else {
    for (int b = 0; b < 4; ++b) {
      gemm_bt<BIAS_NONE, OUT_EXP><<<dim3(32, 32, 1), 256, 0, stream>>>(
          q + b * sBC, 0, 512, k + b * sBC, 0, 512, S, 0, 4096,
          nullptr, nullptr, nullptr, 0, 512, 1.f);
      gemm_pv11<<<dim3(64, 2, 1), 256, LDS_PV, stream>>>(
          S, 0, v + b * sBC, 0, O + b * sBC, 0, 0);
    }
  }

  // out[b,o,n] = wo[o,:] . O[b,n,:] + bo[o] + x[b,o,n]
  gemm_bt<BIAS_ROW, OUT_F32_RESID><<<dim3(4, 32, 4), 256, 0, stream>>>(
      wob, 0, 512, O, sBC, 512, out, sBC, 4096,
      bo, nullptr, x, sBC, 512, 1.f);
}